// Round 8
// baseline (1111.394 us; speedup 1.0000x reference)
//
#include <hip/hip_runtime.h>

// RegressorHybrid: per-edge 2x MLP (128->64->64->32->1, lrelu 0.01), E=2M, H=64.
// Round 8: R6 structure + MLP-split across blocks (blockIdx&1 -> e/w MLP).
//   - R6 was latency-stall-bound (~45% idle) at 8 waves/CU (LDS 57KB + 212 VGPR
//     both cap 2 blocks/CU). Splitting halves LDS (28KB) and hoisted bias regs
//     (96->48) -> 3 blocks/CU, 12 waves/CU, +50% latency hiding.
//   - R7 lesson: spills (584MB scratch) thrash L1 and break the warm->consume
//     reuse -> 4x fills return. launch_bounds(256,3) caps 170 VGPR, no spill.
//   - Warm-pass law (R6-verified): each MISSING b128 lane-request = own 64B
//     fill; warm instr (dword, lane-private line) 3 iters ahead -> consume hits.
// MFMA layouts: A[m=lane&15][k=(lane>>4)*8+j], B[k=(lane>>4)*8+j][n=lane&15],
//               C/D[row=4*(lane>>4)+reg][col=lane&15].

typedef _Float16 half8  __attribute__((ext_vector_type(8)));
typedef _Float16 half4v __attribute__((ext_vector_type(4)));
typedef float    float4v __attribute__((ext_vector_type(4)));

#define LDS_PER_MLP 28672          // w1f 16384 + w2f 8192 + w3f 4096
#define REST_PER_MLP 12288         // w4f 2048 + b1f 4096 + b2f 4096 + b3f 2048
#define W1F 0
#define W2F 16384
#define W3F 24576
#define RW4F 0
#define RB1F 2048
#define RB2F 6144
#define RB3F 10240
#define WS_REST_OFF 57344
#define WS_X16_OFF  81920

__device__ __forceinline__ float lrelu(float x) { return fmaxf(x, 0.01f * x); }

__device__ __forceinline__ int uperm(int k) {
    return 16 * (2 * ((k >> 2) & 1) + ((k >> 5) & 1)) + 4 * ((k >> 3) & 3) + (k & 3);
}

// ---- fused prep: blocks 0..67 e-frags, 68..135 w-frags, rest node f16 ----
__device__ __forceinline__ void pack_frags(int idx,
                           const float* __restrict__ w1, const float* __restrict__ b1,
                           const float* __restrict__ w2, const float* __restrict__ b2,
                           const float* __restrict__ w3, const float* __restrict__ b3,
                           const float* __restrict__ w4,
                           unsigned char* __restrict__ dstL,
                           unsigned char* __restrict__ dstR)
{
    if (idx < 8192) {                      // w1f: [16 frags][64 lanes][8 f16]
        int L = (idx >> 3) & 63, j = idx & 7, f = idx >> 9;
        int q = L >> 4, mm = L & 15, t = f >> 2, s = f & 3;
        int k = 32 * s + 8 * q + j;
        ((_Float16*)(dstL + W1F))[idx] = (_Float16)w1[k * 64 + 16 * t + mm];
        return;
    }
    idx -= 8192;
    if (idx < 4096) {                      // w2f: [8][64][8]
        int L = (idx >> 3) & 63, j = idx & 7, f = idx >> 9;
        int q = L >> 4, mm = L & 15, t = f >> 1, s = f & 1;
        int u = uperm(32 * s + 8 * q + j);
        ((_Float16*)(dstL + W2F))[idx] = (_Float16)w2[u * 64 + 16 * t + mm];
        return;
    }
    idx -= 4096;
    if (idx < 2048) {                      // w3f: [4][64][8]
        int L = (idx >> 3) & 63, j = idx & 7, f = idx >> 9;
        int q = L >> 4, mm = L & 15, t = f >> 1, s = f & 1;
        int u = uperm(32 * s + 8 * q + j);
        ((_Float16*)(dstL + W3F))[idx] = (_Float16)w3[u * 32 + 16 * t + mm];
        return;
    }
    idx -= 2048;
    if (idx < 512) {                       // w4f
        int L = idx >> 3, j = idx & 7;
        int q = L >> 4, t = j >> 2, r = j & 3;
        ((float*)(dstR + RW4F))[idx] = w4[16 * t + 4 * q + r];
        return;
    }
    idx -= 512;
    if (idx < 1024) {                      // b1f: [4 t][64 lanes][4 f32]
        int t = idx >> 8, L = (idx >> 2) & 63, r = idx & 3, q = L >> 4;
        ((float*)(dstR + RB1F))[idx] = b1[16 * t + 4 * q + r];
        return;
    }
    idx -= 1024;
    if (idx < 1024) {                      // b2f
        int t = idx >> 8, L = (idx >> 2) & 63, r = idx & 3, q = L >> 4;
        ((float*)(dstR + RB2F))[idx] = b2[16 * t + 4 * q + r];
        return;
    }
    idx -= 1024;
    if (idx < 512) {                       // b3f
        int t = idx >> 8, L = (idx >> 2) & 63, r = idx & 3, q = L >> 4;
        ((float*)(dstR + RB3F))[idx] = b3[16 * t + 4 * q + r];
        return;
    }
}

__global__ __launch_bounds__(256)
void prep_all(const float* __restrict__ ew1, const float* __restrict__ eb1,
              const float* __restrict__ ew2, const float* __restrict__ eb2,
              const float* __restrict__ ew3, const float* __restrict__ eb3,
              const float* __restrict__ ew4,
              const float* __restrict__ ww1, const float* __restrict__ wb1,
              const float* __restrict__ ww2, const float* __restrict__ wb2,
              const float* __restrict__ ww3, const float* __restrict__ wb3,
              const float* __restrict__ ww4,
              const float* __restrict__ xs, const float* __restrict__ xd,
              _Float16* __restrict__ os, _Float16* __restrict__ od, int n4,
              unsigned char* __restrict__ ws)
{
    int b = blockIdx.x;
    if (b < 68) {
        pack_frags(b * 256 + threadIdx.x, ew1, eb1, ew2, eb2, ew3, eb3, ew4,
                   ws, ws + WS_REST_OFF);
        return;
    }
    if (b < 136) {
        pack_frags((b - 68) * 256 + threadIdx.x, ww1, wb1, ww2, wb2, ww3, wb3, ww4,
                   ws + LDS_PER_MLP, ws + WS_REST_OFF + REST_PER_MLP);
        return;
    }
    int stride = (gridDim.x - 136) * 256;
    for (int i = (b - 136) * 256 + threadIdx.x; i < n4; i += stride) {
        float4v a = ((const float4v*)xs)[i];
        float4v c = ((const float4v*)xd)[i];
        half4v ha, hb;
#pragma unroll
        for (int j = 0; j < 4; ++j) { ha[j] = (_Float16)a[j]; hb[j] = (_Float16)c[j]; }
        ((half4v*)os)[i] = ha;
        ((half4v*)od)[i] = hb;
    }
}

__device__ __forceinline__ half8 repack2(float4v lo, float4v hi) {
    half8 r;
#pragma unroll
    for (int j = 0; j < 4; ++j) r[j] = (_Float16)lrelu(lo[j]);
#pragma unroll
    for (int j = 0; j < 4; ++j) r[4 + j] = (_Float16)lrelu(hi[j]);
    return r;
}

// consume gather (hits warmed lines): lane (q,n) loads chunk q of edge n's lines
__device__ __forceinline__ void gather_tile(const _Float16* __restrict__ xs,
                                            const _Float16* __restrict__ xd,
                                            const int* __restrict__ eidx,
                                            int nE, int tile, int q, int n, int4* G)
{
    int e = tile * 16 + n;
    int ec = e < nE ? e : nE - 1;
    int si = eidx[ec];
    int di = eidx[nE + ec];
    const char* rs = (const char*)(xs + (size_t)si * 64);
    const char* rd = (const char*)(xd + (size_t)di * 64);
    G[0] = *(const int4*)(rs + 16 * q);
    G[1] = *(const int4*)(rs + 64 + 16 * q);
    G[2] = *(const int4*)(rd + 16 * q);
    G[3] = *(const int4*)(rd + 64 + 16 * q);
}

// warm: lane (c=q, n) touches line (edge n, combo c) once -> 64 distinct lines
// per instruction, one 64B fill each. Dword is enough to fill the line.
__device__ __forceinline__ int warm_tile(const _Float16* __restrict__ xs,
                                         const _Float16* __restrict__ xd,
                                         const int* __restrict__ eidx,
                                         int nE, int tile, int c, int n)
{
    int e = tile * 16 + n;
    int ec = e < nE ? e : nE - 1;
    int idx = (c & 2) ? eidx[nE + ec] : eidx[ec];
    const char* base = (const char*)(((c & 2) ? xd : xs) + (size_t)idx * 64);
    return *(const int*)(base + (c & 1) * 64);
}

__global__ __launch_bounds__(256, 3)
void edge_mlp_mfma(const unsigned char* __restrict__ ws,
                   const _Float16* __restrict__ xs, const _Float16* __restrict__ xd,
                   const int* __restrict__ eidx,
                   const float* __restrict__ eb4p, const float* __restrict__ wb4p,
                   float* __restrict__ out, int nE, int ntiles)
{
    __shared__ unsigned char lds[LDS_PER_MLP];
    const int mlp = blockIdx.x & 1;
    {   // stage this block's MLP weight fragments (28KB)
        const uint4* s = (const uint4*)(ws + mlp * LDS_PER_MLP);
        uint4* d = (uint4*)lds;
        for (int i = threadIdx.x; i < LDS_PER_MLP / 16; i += 256) d[i] = s[i];
    }
    __syncthreads();

    const int lane = threadIdx.x & 63;
    const int q = lane >> 4, n = lane & 15;
    const int wid = ((blockIdx.x >> 1) << 2) | (threadIdx.x >> 6);
    const int nwaves = (gridDim.x >> 1) << 2;
    const float b4s = (mlp ? wb4p : eb4p)[0];
    float* __restrict__ outm = out + (size_t)mlp * nE;

    // hoisted bias / w4 fragments for this MLP only (48 VGPRs)
    const unsigned char* rb = ws + WS_REST_OFF + mlp * REST_PER_MLP;
    float4v b1v[4], b2v[4], b3v[2], w4v[2];
#pragma unroll
    for (int t = 0; t < 4; ++t) b1v[t] = *(const float4v*)(rb + RB1F + (t * 64 + lane) * 16);
#pragma unroll
    for (int t = 0; t < 4; ++t) b2v[t] = *(const float4v*)(rb + RB2F + (t * 64 + lane) * 16);
#pragma unroll
    for (int t = 0; t < 2; ++t) b3v[t] = *(const float4v*)(rb + RB3F + (t * 64 + lane) * 16);
    w4v[0] = *(const float4v*)(rb + RW4F + lane * 32);
    w4v[1] = *(const float4v*)(rb + RW4F + lane * 32 + 16);

    int4 Gcur[4], Gnxt[4];
    int W0 = 0, W1 = 0, W2 = 0, junk = 0;

    int tile = wid;
    if (tile < ntiles) {
        int t1 = tile + nwaves;     if (t1 >= ntiles) t1 = ntiles - 1;
        int t2 = tile + 2 * nwaves; if (t2 >= ntiles) t2 = ntiles - 1;
        W0 = warm_tile(xs, xd, eidx, nE, tile, q, n);
        W1 = warm_tile(xs, xd, eidx, nE, t1, q, n);
        W2 = warm_tile(xs, xd, eidx, nE, t2, q, n);
        gather_tile(xs, xd, eidx, nE, tile, q, n, Gcur);
    }

#pragma unroll 1
    for (; tile < ntiles; tile += nwaves) {
        half8 B1[4];
#pragma unroll
        for (int s = 0; s < 4; ++s) B1[s] = __builtin_bit_cast(half8, Gcur[s]);

        // prefetch next tile's consume gather (hits warmed lines)
        int tn = tile + nwaves;
        if (tn < ntiles)
            gather_tile(xs, xd, eidx, nE, tn, q, n, Gnxt);

        // fold oldest warm (2 iters old -> complete), rotate, issue warm iter+3
        junk ^= W0;
        W0 = W1; W1 = W2;
        {
            int tw = tile + 3 * nwaves;
            if (tw >= ntiles) tw = ntiles - 1;
            W2 = warm_tile(xs, xd, eidx, nE, tw, q, n);
        }

        // ---- layer 1: 128 -> 64 (bias via C-init) ----
        float4v acc[4];
#pragma unroll
        for (int t = 0; t < 4; ++t) {
            acc[t] = b1v[t];
#pragma unroll
            for (int s = 0; s < 4; ++s) {
                half8 A = *(const half8*)(lds + W1F + ((t * 4 + s) * 64 + lane) * 16);
                acc[t] = __builtin_amdgcn_mfma_f32_16x16x32_f16(A, B1[s], acc[t], 0, 0, 0);
            }
        }
        // ---- layer 2: 64 -> 64 ----
        half8 B2[2] = { repack2(acc[0], acc[2]), repack2(acc[1], acc[3]) };
        float4v acc2[4];
#pragma unroll
        for (int t = 0; t < 4; ++t) {
            acc2[t] = b2v[t];
#pragma unroll
            for (int s = 0; s < 2; ++s) {
                half8 A = *(const half8*)(lds + W2F + ((t * 2 + s) * 64 + lane) * 16);
                acc2[t] = __builtin_amdgcn_mfma_f32_16x16x32_f16(A, B2[s], acc2[t], 0, 0, 0);
            }
        }
        // ---- layer 3: 64 -> 32 ----
        half8 B3[2] = { repack2(acc2[0], acc2[2]), repack2(acc2[1], acc2[3]) };
        float4v acc3[2];
#pragma unroll
        for (int t = 0; t < 2; ++t) {
            acc3[t] = b3v[t];
#pragma unroll
            for (int s = 0; s < 2; ++s) {
                half8 A = *(const half8*)(lds + W3F + ((t * 2 + s) * 64 + lane) * 16);
                acc3[t] = __builtin_amdgcn_mfma_f32_16x16x32_f16(A, B3[s], acc3[t], 0, 0, 0);
            }
        }
        // ---- layer 4: 32 -> 1 ----
        float o = 0.f;
#pragma unroll
        for (int r = 0; r < 4; ++r) o = fmaf(lrelu(acc3[0][r]), w4v[0][r], o);
#pragma unroll
        for (int r = 0; r < 4; ++r) o = fmaf(lrelu(acc3[1][r]), w4v[1][r], o);
        o += __shfl_xor(o, 16, 64);
        o += __shfl_xor(o, 32, 64);

        int e = tile * 16 + n;
        if (q == 0 && e < nE)
            outm[e] = o + b4s;
#pragma unroll
        for (int s = 0; s < 4; ++s) Gcur[s] = Gnxt[s];
    }

    // consume warm registers (never-taken, data-dependent guard defeats DCE)
    junk ^= W0 ^ W1 ^ W2;
    if (nE < 0 && junk != 0)
        out[0] = -1.0f;
}

extern "C" void kernel_launch(void* const* d_in, const int* in_sizes, int n_in,
                              void* d_out, int out_size, void* d_ws, size_t ws_size,
                              hipStream_t stream)
{
    const float* x_src = (const float*)d_in[0];
    const float* x_dst = (const float*)d_in[1];
    const int*   eidx  = (const int*)d_in[2];
    const float* ew1 = (const float*)d_in[3];
    const float* eb1 = (const float*)d_in[4];
    const float* ww1 = (const float*)d_in[5];
    const float* wb1 = (const float*)d_in[6];
    const float* ew2 = (const float*)d_in[7];
    const float* eb2 = (const float*)d_in[8];
    const float* ww2 = (const float*)d_in[9];
    const float* wb2 = (const float*)d_in[10];
    const float* ew3 = (const float*)d_in[11];
    const float* eb3 = (const float*)d_in[12];
    const float* ww3 = (const float*)d_in[13];
    const float* wb3 = (const float*)d_in[14];
    const float* ew4 = (const float*)d_in[15];
    const float* eb4 = (const float*)d_in[16];
    const float* ww4 = (const float*)d_in[17];
    const float* wb4 = (const float*)d_in[18];
    float* out = (float*)d_out;

    const int nE = in_sizes[2] / 2;          // 2 x E index array (int32)
    const int nNodeElems = in_sizes[0];      // N_NODES * 64
    unsigned char* ws = (unsigned char*)d_ws;
    _Float16* xs16 = (_Float16*)(ws + WS_X16_OFF);
    _Float16* xd16 = xs16 + nNodeElems;

    prep_all<<<1024, 256, 0, stream>>>(ew1, eb1, ew2, eb2, ew3, eb3, ew4,
                                       ww1, wb1, ww2, wb2, ww3, wb3, ww4,
                                       x_src, x_dst, xs16, xd16, nNodeElems / 4, ws);

    const int ntiles = (nE + 15) / 16;
    edge_mlp_mfma<<<1024, 256, 0, stream>>>(ws, xs16, xd16, eidx, eb4, wb4,
                                            out, nE, ntiles);
}

// Round 10
// 891.598 us; speedup vs baseline: 1.2465x; 1.2465x over previous
//
#include <hip/hip_runtime.h>

// RegressorHybrid: per-edge 2x MLP (128->64->64->32->1, lrelu 0.01), E=2M, H=64.
// Round 10 (= R9 with cvt_pkrtz type fix): R6 structure (verified best:
// warm-pass gather, both MLPs per wave, 2 blocks/CU) + two stall cuts:
//   (1) packed-f16 repack: v_cvt_pkrtz + v_pk_mul/v_pk_max (12 VALU/8 vals vs 24)
//   (2) explicit layer-by-layer interleave of the two independent MLPs:
//       per (t,s) two LDS A-reads + two MFMAs on independent accumulators ->
//       2x independent chains at layer boundaries (R6 was ~45% stall).
// Memory laws (R1-R8 verified):
//   - each MISSING b128 lane-request = own 64B fill (no intra-instr merge);
//     temporally-separated re-touches hit L1/L2; warm instr (lane-private
//     line, dword) 3 iters ahead -> consume hits. FETCH 2.5GB -> 185MB (R6).
//   - warm->consume works only if in-flight lines fit per-XCD L2 (4MB):
//     R6's 256 waves/XCD * 4KB * 3 iters ~ 3MB fits; R8's split overflowed.
//   - spills thrash L1 and break warm->consume (R7): WRITE_SIZE is the tripwire.
// MFMA layouts: A[m=lane&15][k=(lane>>4)*8+j], B[k=(lane>>4)*8+j][n=lane&15],
//               C/D[row=4*(lane>>4)+reg][col=lane&15].

typedef _Float16 half8  __attribute__((ext_vector_type(8)));
typedef _Float16 half4v __attribute__((ext_vector_type(4)));
typedef _Float16 half2v __attribute__((ext_vector_type(2)));
typedef __fp16   fp16v2 __attribute__((ext_vector_type(2)));
typedef float    float4v __attribute__((ext_vector_type(4)));

#define LDS_PER_MLP 28672          // w1f 16384 + w2f 8192 + w3f 4096
#define LDS_TOTAL   57344
#define REST_PER_MLP 12288         // w4f 2048 + b1f 4096 + b2f 4096 + b3f 2048
#define W1F 0
#define W2F 16384
#define W3F 24576
#define RW4F 0
#define RB1F 2048
#define RB2F 6144
#define RB3F 10240
#define WS_REST_OFF 57344
#define WS_X16_OFF  81920

__device__ __forceinline__ float lrelu(float x) { return fmaxf(x, 0.01f * x); }

__device__ __forceinline__ int uperm(int k) {
    return 16 * (2 * ((k >> 2) & 1) + ((k >> 5) & 1)) + 4 * ((k >> 3) & 3) + (k & 3);
}

// ---- fused prep: blocks 0..67 e-frags, 68..135 w-frags, rest node f16 ----
__device__ __forceinline__ void pack_frags(int idx,
                           const float* __restrict__ w1, const float* __restrict__ b1,
                           const float* __restrict__ w2, const float* __restrict__ b2,
                           const float* __restrict__ w3, const float* __restrict__ b3,
                           const float* __restrict__ w4,
                           unsigned char* __restrict__ dstL,
                           unsigned char* __restrict__ dstR)
{
    if (idx < 8192) {                      // w1f: [16 frags][64 lanes][8 f16]
        int L = (idx >> 3) & 63, j = idx & 7, f = idx >> 9;
        int q = L >> 4, mm = L & 15, t = f >> 2, s = f & 3;
        int k = 32 * s + 8 * q + j;
        ((_Float16*)(dstL + W1F))[idx] = (_Float16)w1[k * 64 + 16 * t + mm];
        return;
    }
    idx -= 8192;
    if (idx < 4096) {                      // w2f: [8][64][8]
        int L = (idx >> 3) & 63, j = idx & 7, f = idx >> 9;
        int q = L >> 4, mm = L & 15, t = f >> 1, s = f & 1;
        int u = uperm(32 * s + 8 * q + j);
        ((_Float16*)(dstL + W2F))[idx] = (_Float16)w2[u * 64 + 16 * t + mm];
        return;
    }
    idx -= 4096;
    if (idx < 2048) {                      // w3f: [4][64][8]
        int L = (idx >> 3) & 63, j = idx & 7, f = idx >> 9;
        int q = L >> 4, mm = L & 15, t = f >> 1, s = f & 1;
        int u = uperm(32 * s + 8 * q + j);
        ((_Float16*)(dstL + W3F))[idx] = (_Float16)w3[u * 32 + 16 * t + mm];
        return;
    }
    idx -= 2048;
    if (idx < 512) {                       // w4f
        int L = idx >> 3, j = idx & 7;
        int q = L >> 4, t = j >> 2, r = j & 3;
        ((float*)(dstR + RW4F))[idx] = w4[16 * t + 4 * q + r];
        return;
    }
    idx -= 512;
    if (idx < 1024) {                      // b1f: [4 t][64 lanes][4 f32]
        int t = idx >> 8, L = (idx >> 2) & 63, r = idx & 3, q = L >> 4;
        ((float*)(dstR + RB1F))[idx] = b1[16 * t + 4 * q + r];
        return;
    }
    idx -= 1024;
    if (idx < 1024) {                      // b2f
        int t = idx >> 8, L = (idx >> 2) & 63, r = idx & 3, q = L >> 4;
        ((float*)(dstR + RB2F))[idx] = b2[16 * t + 4 * q + r];
        return;
    }
    idx -= 1024;
    if (idx < 512) {                       // b3f
        int t = idx >> 8, L = (idx >> 2) & 63, r = idx & 3, q = L >> 4;
        ((float*)(dstR + RB3F))[idx] = b3[16 * t + 4 * q + r];
        return;
    }
}

__global__ __launch_bounds__(256)
void prep_all(const float* __restrict__ ew1, const float* __restrict__ eb1,
              const float* __restrict__ ew2, const float* __restrict__ eb2,
              const float* __restrict__ ew3, const float* __restrict__ eb3,
              const float* __restrict__ ew4,
              const float* __restrict__ ww1, const float* __restrict__ wb1,
              const float* __restrict__ ww2, const float* __restrict__ wb2,
              const float* __restrict__ ww3, const float* __restrict__ wb3,
              const float* __restrict__ ww4,
              const float* __restrict__ xs, const float* __restrict__ xd,
              _Float16* __restrict__ os, _Float16* __restrict__ od, int n4,
              unsigned char* __restrict__ ws)
{
    int b = blockIdx.x;
    if (b < 68) {
        pack_frags(b * 256 + threadIdx.x, ew1, eb1, ew2, eb2, ew3, eb3, ew4,
                   ws, ws + WS_REST_OFF);
        return;
    }
    if (b < 136) {
        pack_frags((b - 68) * 256 + threadIdx.x, ww1, wb1, ww2, wb2, ww3, wb3, ww4,
                   ws + LDS_PER_MLP, ws + WS_REST_OFF + REST_PER_MLP);
        return;
    }
    int stride = (gridDim.x - 136) * 256;
    for (int i = (b - 136) * 256 + threadIdx.x; i < n4; i += stride) {
        float4v a = ((const float4v*)xs)[i];
        float4v c = ((const float4v*)xd)[i];
        half4v ha, hb;
#pragma unroll
        for (int j = 0; j < 4; ++j) { ha[j] = (_Float16)a[j]; hb[j] = (_Float16)c[j]; }
        ((half4v*)os)[i] = ha;
        ((half4v*)od)[i] = hb;
    }
}

// packed repack: f32x4+f32x4 -> lrelu -> half8, via pkrtz + pk_mul + pk_max
__device__ __forceinline__ half2v pkrtz(float a, float b) {
    return __builtin_bit_cast(half2v, __builtin_amdgcn_cvt_pkrtz(a, b));
}
__device__ __forceinline__ half8 repack2(float4v lo, float4v hi) {
    half2v p0 = pkrtz(lo[0], lo[1]);
    half2v p1 = pkrtz(lo[2], lo[3]);
    half2v p2 = pkrtz(hi[0], hi[1]);
    half2v p3 = pkrtz(hi[2], hi[3]);
    const half2v k = { (_Float16)0.01f, (_Float16)0.01f };
    p0 = __builtin_elementwise_max(p0, p0 * k);
    p1 = __builtin_elementwise_max(p1, p1 * k);
    p2 = __builtin_elementwise_max(p2, p2 * k);
    p3 = __builtin_elementwise_max(p3, p3 * k);
    half8 r = { p0[0], p0[1], p1[0], p1[1], p2[0], p2[1], p3[0], p3[1] };
    return r;
}

// consume gather (hits warmed lines): lane (q,n) loads chunk q of edge n's lines
__device__ __forceinline__ void gather_tile(const _Float16* __restrict__ xs,
                                            const _Float16* __restrict__ xd,
                                            const int* __restrict__ eidx,
                                            int nE, int tile, int q, int n, int4* G)
{
    int e = tile * 16 + n;
    int ec = e < nE ? e : nE - 1;
    int si = eidx[ec];
    int di = eidx[nE + ec];
    const char* rs = (const char*)(xs + (size_t)si * 64);
    const char* rd = (const char*)(xd + (size_t)di * 64);
    G[0] = *(const int4*)(rs + 16 * q);
    G[1] = *(const int4*)(rs + 64 + 16 * q);
    G[2] = *(const int4*)(rd + 16 * q);
    G[3] = *(const int4*)(rd + 64 + 16 * q);
}

// warm: lane (c=q, n) touches line (edge n, combo c) once -> 64 distinct lines
// per instruction, one 64B fill each.
__device__ __forceinline__ int warm_tile(const _Float16* __restrict__ xs,
                                         const _Float16* __restrict__ xd,
                                         const int* __restrict__ eidx,
                                         int nE, int tile, int c, int n)
{
    int e = tile * 16 + n;
    int ec = e < nE ? e : nE - 1;
    int idx = (c & 2) ? eidx[nE + ec] : eidx[ec];
    const char* base = (const char*)(((c & 2) ? xd : xs) + (size_t)idx * 64);
    return *(const int*)(base + (c & 1) * 64);
}

__global__ __launch_bounds__(256, 2)
void edge_mlp_mfma(const unsigned char* __restrict__ ws,
                   const _Float16* __restrict__ xs, const _Float16* __restrict__ xd,
                   const int* __restrict__ eidx,
                   const float* __restrict__ eb4p, const float* __restrict__ wb4p,
                   float* __restrict__ out, int nE, int ntiles)
{
    __shared__ unsigned char lds[LDS_TOTAL];
    {
        const uint4* s = (const uint4*)ws;
        uint4* d = (uint4*)lds;
        for (int i = threadIdx.x; i < LDS_TOTAL / 16; i += 256) d[i] = s[i];
    }
    __syncthreads();

    const int lane = threadIdx.x & 63;
    const int q = lane >> 4, n = lane & 15;
    const int wid = (blockIdx.x << 2) | (threadIdx.x >> 6);
    const int nwaves = gridDim.x << 2;
    const float b4s0 = eb4p[0], b4s1 = wb4p[0];

    // hoisted bias / w4 fragments (both MLPs, loop-invariant)
    float4v b1v[2][4], b2v[2][4], b3v[2][2], w4v[2][2];
#pragma unroll
    for (int m = 0; m < 2; ++m) {
        const unsigned char* rb = ws + WS_REST_OFF + m * REST_PER_MLP;
#pragma unroll
        for (int t = 0; t < 4; ++t) b1v[m][t] = *(const float4v*)(rb + RB1F + (t * 64 + lane) * 16);
#pragma unroll
        for (int t = 0; t < 4; ++t) b2v[m][t] = *(const float4v*)(rb + RB2F + (t * 64 + lane) * 16);
#pragma unroll
        for (int t = 0; t < 2; ++t) b3v[m][t] = *(const float4v*)(rb + RB3F + (t * 64 + lane) * 16);
        w4v[m][0] = *(const float4v*)(rb + RW4F + lane * 32);
        w4v[m][1] = *(const float4v*)(rb + RW4F + lane * 32 + 16);
    }

    int4 Gcur[4], Gnxt[4];
    int W0 = 0, W1 = 0, W2 = 0, junk = 0;

    int tile = wid;
    if (tile < ntiles) {
        int t1 = tile + nwaves;     if (t1 >= ntiles) t1 = ntiles - 1;
        int t2 = tile + 2 * nwaves; if (t2 >= ntiles) t2 = ntiles - 1;
        W0 = warm_tile(xs, xd, eidx, nE, tile, q, n);
        W1 = warm_tile(xs, xd, eidx, nE, t1, q, n);
        W2 = warm_tile(xs, xd, eidx, nE, t2, q, n);
        gather_tile(xs, xd, eidx, nE, tile, q, n, Gcur);
    }

#pragma unroll 1
    for (; tile < ntiles; tile += nwaves) {
        half8 B1[4];
#pragma unroll
        for (int s = 0; s < 4; ++s) B1[s] = __builtin_bit_cast(half8, Gcur[s]);

        // prefetch next tile's consume gather (hits warmed lines)
        int tn = tile + nwaves;
        if (tn < ntiles)
            gather_tile(xs, xd, eidx, nE, tn, q, n, Gnxt);

        // fold oldest warm (2 iters old -> complete), rotate, issue warm iter+3
        junk ^= W0;
        W0 = W1; W1 = W2;
        {
            int tw = tile + 3 * nwaves;
            if (tw >= ntiles) tw = ntiles - 1;
            W2 = warm_tile(xs, xd, eidx, nE, tw, q, n);
        }

        // ---- layer 1 (both MLPs interleaved): 128 -> 64 ----
        float4v a1[2][4];
#pragma unroll
        for (int t = 0; t < 4; ++t) {
            a1[0][t] = b1v[0][t];
            a1[1][t] = b1v[1][t];
#pragma unroll
            for (int s = 0; s < 4; ++s) {
                half8 A0 = *(const half8*)(lds + W1F + ((t * 4 + s) * 64 + lane) * 16);
                half8 A1 = *(const half8*)(lds + LDS_PER_MLP + W1F + ((t * 4 + s) * 64 + lane) * 16);
                a1[0][t] = __builtin_amdgcn_mfma_f32_16x16x32_f16(A0, B1[s], a1[0][t], 0, 0, 0);
                a1[1][t] = __builtin_amdgcn_mfma_f32_16x16x32_f16(A1, B1[s], a1[1][t], 0, 0, 0);
            }
        }
        // ---- layer 2 (both MLPs interleaved): 64 -> 64 ----
        half8 B2[2][2];
#pragma unroll
        for (int m = 0; m < 2; ++m) {
            B2[m][0] = repack2(a1[m][0], a1[m][2]);
            B2[m][1] = repack2(a1[m][1], a1[m][3]);
        }
        float4v a2[2][4];
#pragma unroll
        for (int t = 0; t < 4; ++t) {
            a2[0][t] = b2v[0][t];
            a2[1][t] = b2v[1][t];
#pragma unroll
            for (int s = 0; s < 2; ++s) {
                half8 A0 = *(const half8*)(lds + W2F + ((t * 2 + s) * 64 + lane) * 16);
                half8 A1 = *(const half8*)(lds + LDS_PER_MLP + W2F + ((t * 2 + s) * 64 + lane) * 16);
                a2[0][t] = __builtin_amdgcn_mfma_f32_16x16x32_f16(A0, B2[0][s], a2[0][t], 0, 0, 0);
                a2[1][t] = __builtin_amdgcn_mfma_f32_16x16x32_f16(A1, B2[1][s], a2[1][t], 0, 0, 0);
            }
        }
        // ---- layer 3 (both MLPs interleaved): 64 -> 32 ----
        half8 B3[2][2];
#pragma unroll
        for (int m = 0; m < 2; ++m) {
            B3[m][0] = repack2(a2[m][0], a2[m][2]);
            B3[m][1] = repack2(a2[m][1], a2[m][3]);
        }
        float4v a3[2][2];
#pragma unroll
        for (int t = 0; t < 2; ++t) {
            a3[0][t] = b3v[0][t];
            a3[1][t] = b3v[1][t];
#pragma unroll
            for (int s = 0; s < 2; ++s) {
                half8 A0 = *(const half8*)(lds + W3F + ((t * 2 + s) * 64 + lane) * 16);
                half8 A1 = *(const half8*)(lds + LDS_PER_MLP + W3F + ((t * 2 + s) * 64 + lane) * 16);
                a3[0][t] = __builtin_amdgcn_mfma_f32_16x16x32_f16(A0, B3[0][s], a3[0][t], 0, 0, 0);
                a3[1][t] = __builtin_amdgcn_mfma_f32_16x16x32_f16(A1, B3[1][s], a3[1][t], 0, 0, 0);
            }
        }
        // ---- layer 4 (both MLPs): 32 -> 1 ----
        float o0 = 0.f, o1 = 0.f;
#pragma unroll
        for (int r = 0; r < 4; ++r) {
            o0 = fmaf(lrelu(a3[0][0][r]), w4v[0][0][r], o0);
            o1 = fmaf(lrelu(a3[1][0][r]), w4v[1][0][r], o1);
        }
#pragma unroll
        for (int r = 0; r < 4; ++r) {
            o0 = fmaf(lrelu(a3[0][1][r]), w4v[0][1][r], o0);
            o1 = fmaf(lrelu(a3[1][1][r]), w4v[1][1][r], o1);
        }
        o0 += __shfl_xor(o0, 16, 64); o0 += __shfl_xor(o0, 32, 64);
        o1 += __shfl_xor(o1, 16, 64); o1 += __shfl_xor(o1, 32, 64);

        int e = tile * 16 + n;
        if (q == 0 && e < nE) {
            out[e] = o0 + b4s0;
            out[nE + e] = o1 + b4s1;
        }
#pragma unroll
        for (int s = 0; s < 4; ++s) Gcur[s] = Gnxt[s];
    }

    // consume warm registers (never-taken, data-dependent guard defeats DCE)
    junk ^= W0 ^ W1 ^ W2;
    if (nE < 0 && junk != 0)
        out[0] = -1.0f;
}

extern "C" void kernel_launch(void* const* d_in, const int* in_sizes, int n_in,
                              void* d_out, int out_size, void* d_ws, size_t ws_size,
                              hipStream_t stream)
{
    const float* x_src = (const float*)d_in[0];
    const float* x_dst = (const float*)d_in[1];
    const int*   eidx  = (const int*)d_in[2];
    const float* ew1 = (const float*)d_in[3];
    const float* eb1 = (const float*)d_in[4];
    const float* ww1 = (const float*)d_in[5];
    const float* wb1 = (const float*)d_in[6];
    const float* ew2 = (const float*)d_in[7];
    const float* eb2 = (const float*)d_in[8];
    const float* ww2 = (const float*)d_in[9];
    const float* wb2 = (const float*)d_in[10];
    const float* ew3 = (const float*)d_in[11];
    const float* eb3 = (const float*)d_in[12];
    const float* ww3 = (const float*)d_in[13];
    const float* wb3 = (const float*)d_in[14];
    const float* ew4 = (const float*)d_in[15];
    const float* eb4 = (const float*)d_in[16];
    const float* ww4 = (const float*)d_in[17];
    const float* wb4 = (const float*)d_in[18];
    float* out = (float*)d_out;

    const int nE = in_sizes[2] / 2;          // 2 x E index array (int32)
    const int nNodeElems = in_sizes[0];      // N_NODES * 64
    unsigned char* ws = (unsigned char*)d_ws;
    _Float16* xs16 = (_Float16*)(ws + WS_X16_OFF);
    _Float16* xd16 = xs16 + nNodeElems;

    prep_all<<<1024, 256, 0, stream>>>(ew1, eb1, ew2, eb2, ew3, eb3, ew4,
                                       ww1, wb1, ww2, wb2, ww3, wb3, ww4,
                                       x_src, x_dst, xs16, xd16, nNodeElems / 4, ws);

    const int ntiles = (nE + 15) / 16;
    edge_mlp_mfma<<<512, 256, 0, stream>>>(ws, xs16, xd16, eidx, eb4, wb4,
                                           out, nE, ntiles);
}